// Round 1
// baseline (1179.052 us; speedup 1.0000x reference)
//
#include <hip/hip_runtime.h>
#include <hip/hip_bf16.h>

#define T 2048
#define H 1024
#define IDIM 512
#define E 16
#define TOPK 4
#define NPAIR (T * TOPK)

#define KH 16
#define LSTR 68  // 64 + 4 pad; 68*4B = 272B keeps float4 alignment per row

// ---------------- Router: one wave per token ----------------
__global__ __launch_bounds__(256) void router_kernel(
    const float* __restrict__ x, const float* __restrict__ gw,
    int* __restrict__ topk_idx, float* __restrict__ topk_w,
    int* __restrict__ counts)
{
    int wave = blockIdx.x * 4 + (threadIdx.x >> 6);
    int lane = threadIdx.x & 63;
    if (wave >= T) return;
    const float* xt = x + (size_t)wave * H;
    float xr[16];
#pragma unroll
    for (int j = 0; j < 16; ++j) xr[j] = xt[lane + j * 64];
    float logits[E];
#pragma unroll
    for (int e = 0; e < E; ++e) {
        const float* ge = gw + e * H;
        float acc = 0.f;
#pragma unroll
        for (int j = 0; j < 16; ++j) acc += xr[j] * ge[lane + j * 64];
#pragma unroll
        for (int off = 32; off; off >>= 1) acc += __shfl_xor(acc, off, 64);
        logits[e] = acc;
    }
    if (lane == 0) {
        float m = logits[0];
#pragma unroll
        for (int e = 1; e < E; ++e) m = fmaxf(m, logits[e]);
        float p[E];
#pragma unroll
        for (int e = 0; e < E; ++e) p[e] = __expf(logits[e] - m);
        int sel[TOPK]; float wv[TOPK]; float tot = 0.f;
#pragma unroll
        for (int k = 0; k < TOPK; ++k) {
            int best = 0; float bv = -1.f;
#pragma unroll
            for (int e = 0; e < E; ++e) { if (p[e] > bv) { bv = p[e]; best = e; } }
            sel[k] = best; wv[k] = bv; tot += bv; p[best] = -2.f;
        }
#pragma unroll
        for (int k = 0; k < TOPK; ++k) {
            topk_idx[wave * TOPK + k] = sel[k];
            topk_w[wave * TOPK + k] = wv[k] / tot;  // softmax denom cancels in renorm
            atomicAdd(&counts[sel[k]], 1);
        }
    }
}

// ---------------- Exclusive scan over 16 experts ----------------
__global__ void scan_kernel(const int* __restrict__ counts, int* __restrict__ offsets)
{
    if (threadIdx.x == 0 && blockIdx.x == 0) {
        int s = 0;
#pragma unroll
        for (int e = 0; e < E; ++e) { offsets[e] = s; s += counts[e]; }
        offsets[E] = s;
    }
}

// ---------------- Scatter pairs into expert-grouped lists ----------------
__global__ __launch_bounds__(256) void scatter_kernel(
    const int* __restrict__ topk_idx, const float* __restrict__ topk_w,
    const int* __restrict__ offsets, int* __restrict__ cursor,
    int* __restrict__ pair_token, float* __restrict__ pair_w)
{
    int i = blockIdx.x * blockDim.x + threadIdx.x;
    if (i >= NPAIR) return;
    int e = topk_idx[i];
    int pos = offsets[e] + atomicAdd(&cursor[e], 1);
    pair_token[pos] = i >> 2;
    pair_w[pos] = topk_w[i];
}

// ---------------- FFN stage A: act = silu(x@w1^T) * (x@w3^T), grouped ----------------
// block: 256 threads, tile = 64 tokens x 64 intermediate, K-chunk = 16 over H
__global__ __launch_bounds__(256) void ffn_a_kernel(
    const float* __restrict__ x, const float* __restrict__ w1,
    const float* __restrict__ w3, const int* __restrict__ offsets,
    const int* __restrict__ pair_token, float* __restrict__ act)
{
    __shared__ __align__(16) float Xs[KH][LSTR];
    __shared__ __align__(16) float W1s[KH][LSTR];
    __shared__ __align__(16) float W3s[KH][LSTR];

    int e = blockIdx.z;
    int beg = offsets[e];
    int cnt = offsets[e + 1] - beg;
    int t0 = blockIdx.x * 64;
    if (t0 >= cnt) return;
    int i0 = blockIdx.y * 64;

    int tid = threadIdx.x;
    int lt = tid >> 2;   // 0..63: row this thread loads
    int kq = tid & 3;    // which float4 along k

    bool rowv = (t0 + lt) < cnt;
    int tok = rowv ? pair_token[beg + t0 + lt] : 0;
    const float* xrow = x + (size_t)tok * H;
    const float* w1e = w1 + (size_t)e * IDIM * H + (size_t)(i0 + lt) * H;
    const float* w3e = w3 + (size_t)e * IDIM * H + (size_t)(i0 + lt) * H;

    int tx = tid & 15, ty = tid >> 4;
    float acc1[4][4] = {{0.f}}, acc3[4][4] = {{0.f}};

    for (int h0 = 0; h0 < H; h0 += KH) {
        float4 xv = make_float4(0.f, 0.f, 0.f, 0.f);
        if (rowv) xv = *(const float4*)(xrow + h0 + kq * 4);
        float4 av = *(const float4*)(w1e + h0 + kq * 4);
        float4 bv = *(const float4*)(w3e + h0 + kq * 4);
        __syncthreads();
        Xs[kq * 4 + 0][lt] = xv.x; Xs[kq * 4 + 1][lt] = xv.y;
        Xs[kq * 4 + 2][lt] = xv.z; Xs[kq * 4 + 3][lt] = xv.w;
        W1s[kq * 4 + 0][lt] = av.x; W1s[kq * 4 + 1][lt] = av.y;
        W1s[kq * 4 + 2][lt] = av.z; W1s[kq * 4 + 3][lt] = av.w;
        W3s[kq * 4 + 0][lt] = bv.x; W3s[kq * 4 + 1][lt] = bv.y;
        W3s[kq * 4 + 2][lt] = bv.z; W3s[kq * 4 + 3][lt] = bv.w;
        __syncthreads();
#pragma unroll
        for (int k = 0; k < KH; ++k) {
            float4 xa = *(const float4*)&Xs[k][ty * 4];
            float4 wa = *(const float4*)&W1s[k][tx * 4];
            float4 wb = *(const float4*)&W3s[k][tx * 4];
            float xs[4] = {xa.x, xa.y, xa.z, xa.w};
            float was[4] = {wa.x, wa.y, wa.z, wa.w};
            float wbs[4] = {wb.x, wb.y, wb.z, wb.w};
#pragma unroll
            for (int r = 0; r < 4; ++r)
#pragma unroll
                for (int c = 0; c < 4; ++c) {
                    acc1[r][c] += xs[r] * was[c];
                    acc3[r][c] += xs[r] * wbs[c];
                }
        }
    }
#pragma unroll
    for (int r = 0; r < 4; ++r) {
        int trow = t0 + ty * 4 + r;
        if (trow < cnt) {
            float4 o;
            float* op = (float*)&o;
#pragma unroll
            for (int c = 0; c < 4; ++c) {
                float h1 = acc1[r][c];
                float s = h1 / (1.f + __expf(-h1));   // silu
                op[c] = s * acc3[r][c];
            }
            *(float4*)(act + (size_t)(beg + trow) * IDIM + i0 + tx * 4) = o;
        }
    }
}

// ---------------- FFN stage B: out[tok,:] += w_pair * act @ w2^T ----------------
// block: 256 threads, tile = 64 tokens x 64 H, K-chunk = 16 over IDIM
__global__ __launch_bounds__(256) void ffn_b_kernel(
    const float* __restrict__ act, const float* __restrict__ w2,
    const int* __restrict__ offsets, const int* __restrict__ pair_token,
    const float* __restrict__ pair_w, float* __restrict__ out)
{
    __shared__ __align__(16) float As[KH][LSTR];
    __shared__ __align__(16) float W2s[KH][LSTR];

    int e = blockIdx.z;
    int beg = offsets[e];
    int cnt = offsets[e + 1] - beg;
    int t0 = blockIdx.x * 64;
    if (t0 >= cnt) return;
    int h0 = blockIdx.y * 64;

    int tid = threadIdx.x;
    int lt = tid >> 2, kq = tid & 3;
    bool rowv = (t0 + lt) < cnt;
    const float* arow = act + (size_t)(beg + t0 + (rowv ? lt : 0)) * IDIM;
    const float* w2e = w2 + (size_t)e * H * IDIM + (size_t)(h0 + lt) * IDIM;

    int tx = tid & 15, ty = tid >> 4;
    float acc[4][4] = {{0.f}};

    for (int ic = 0; ic < IDIM; ic += KH) {
        float4 av = make_float4(0.f, 0.f, 0.f, 0.f);
        if (rowv) av = *(const float4*)(arow + ic + kq * 4);
        float4 wv = *(const float4*)(w2e + ic + kq * 4);
        __syncthreads();
        As[kq * 4 + 0][lt] = av.x; As[kq * 4 + 1][lt] = av.y;
        As[kq * 4 + 2][lt] = av.z; As[kq * 4 + 3][lt] = av.w;
        W2s[kq * 4 + 0][lt] = wv.x; W2s[kq * 4 + 1][lt] = wv.y;
        W2s[kq * 4 + 2][lt] = wv.z; W2s[kq * 4 + 3][lt] = wv.w;
        __syncthreads();
#pragma unroll
        for (int k = 0; k < KH; ++k) {
            float4 aa = *(const float4*)&As[k][ty * 4];
            float4 ww = *(const float4*)&W2s[k][tx * 4];
            float as[4] = {aa.x, aa.y, aa.z, aa.w};
            float wsv[4] = {ww.x, ww.y, ww.z, ww.w};
#pragma unroll
            for (int r = 0; r < 4; ++r)
#pragma unroll
                for (int c = 0; c < 4; ++c)
                    acc[r][c] += as[r] * wsv[c];
        }
    }
#pragma unroll
    for (int r = 0; r < 4; ++r) {
        int trow = t0 + ty * 4 + r;
        if (trow < cnt) {
            int tok = pair_token[beg + trow];
            float pw = pair_w[beg + trow];
            float* orow = out + (size_t)tok * H + h0 + tx * 4;
#pragma unroll
            for (int c = 0; c < 4; ++c) atomicAdd(&orow[c], pw * acc[r][c]);
        }
    }
}

extern "C" void kernel_launch(void* const* d_in, const int* in_sizes, int n_in,
                              void* d_out, int out_size, void* d_ws, size_t ws_size,
                              hipStream_t stream)
{
    const float* x  = (const float*)d_in[0];
    const float* gw = (const float*)d_in[1];
    const float* w1 = (const float*)d_in[2];
    const float* w3 = (const float*)d_in[3];
    const float* w2 = (const float*)d_in[4];
    float* out = (float*)d_out;

    char* ws = (char*)d_ws;
    int*   counts     = (int*)(ws + 0);       // 16 ints
    int*   cursor     = (int*)(ws + 64);      // 16 ints
    int*   offsets    = (int*)(ws + 128);     // 17 ints
    int*   topk_idx   = (int*)(ws + 4096);    // NPAIR ints
    float* topk_w     = (float*)(ws + 36864); // NPAIR floats
    int*   pair_token = (int*)(ws + 69632);   // NPAIR ints
    float* pair_w     = (float*)(ws + 102400);// NPAIR floats
    float* act        = (float*)(ws + 262144);// NPAIR x IDIM floats (16 MB)

    hipMemsetAsync(ws, 0, 256, stream);                       // counts/cursor/offsets
    hipMemsetAsync(d_out, 0, (size_t)T * H * sizeof(float), stream);

    router_kernel<<<T / 4, 256, 0, stream>>>(x, gw, topk_idx, topk_w, counts);
    scan_kernel<<<1, 64, 0, stream>>>(counts, offsets);
    scatter_kernel<<<NPAIR / 256, 256, 0, stream>>>(topk_idx, topk_w, offsets, cursor,
                                                    pair_token, pair_w);
    ffn_a_kernel<<<dim3(32, IDIM / 64, E), 256, 0, stream>>>(x, w1, w3, offsets,
                                                             pair_token, act);
    ffn_b_kernel<<<dim3(32, H / 64, E), 256, 0, stream>>>(act, w2, offsets,
                                                          pair_token, pair_w, out);
}

// Round 2
// 491.496 us; speedup vs baseline: 2.3989x; 2.3989x over previous
//
#include <hip/hip_runtime.h>
#include <hip/hip_bf16.h>

#define T 2048
#define H 1024
#define IDIM 512
#define E 16
#define TOPK 4
#define NPAIR (T * TOPK)

typedef short bf16x8 __attribute__((ext_vector_type(8)));
typedef float f32x4 __attribute__((ext_vector_type(4)));

static __device__ __forceinline__ unsigned short f2bf(float f) {
    union { float f; unsigned int u; } v; v.f = f;
    unsigned int r = (v.u + 0x7FFFu + ((v.u >> 16) & 1u)) >> 16;  // RNE
    return (unsigned short)r;
}

// ---------------- fp32 -> bf16 bulk convert (memory-bound) ----------------
__global__ __launch_bounds__(256) void cvt_kernel(
    const float* __restrict__ src, unsigned short* __restrict__ dst, int n4)
{
    int i = blockIdx.x * blockDim.x + threadIdx.x;
    int stride = gridDim.x * blockDim.x;
    for (; i < n4; i += stride) {
        float4 v = ((const float4*)src)[i];
        ushort4 o;
        o.x = f2bf(v.x); o.y = f2bf(v.y); o.z = f2bf(v.z); o.w = f2bf(v.w);
        ((ushort4*)dst)[i] = o;
    }
}

// ---------------- Router: one wave per token (fp32, exact routing) ----------------
__global__ __launch_bounds__(256) void router_kernel(
    const float* __restrict__ x, const float* __restrict__ gw,
    int* __restrict__ topk_idx, float* __restrict__ topk_w,
    int* __restrict__ counts)
{
    int wave = blockIdx.x * 4 + (threadIdx.x >> 6);
    int lane = threadIdx.x & 63;
    if (wave >= T) return;
    const float* xt = x + (size_t)wave * H;
    float xr[16];
#pragma unroll
    for (int j = 0; j < 16; ++j) xr[j] = xt[lane + j * 64];
    float logits[E];
#pragma unroll
    for (int e = 0; e < E; ++e) {
        const float* ge = gw + e * H;
        float acc = 0.f;
#pragma unroll
        for (int j = 0; j < 16; ++j) acc += xr[j] * ge[lane + j * 64];
#pragma unroll
        for (int off = 32; off; off >>= 1) acc += __shfl_xor(acc, off, 64);
        logits[e] = acc;
    }
    if (lane == 0) {
        float m = logits[0];
#pragma unroll
        for (int e = 1; e < E; ++e) m = fmaxf(m, logits[e]);
        float p[E];
#pragma unroll
        for (int e = 0; e < E; ++e) p[e] = __expf(logits[e] - m);
        int sel[TOPK]; float wv[TOPK]; float tot = 0.f;
#pragma unroll
        for (int k = 0; k < TOPK; ++k) {
            int best = 0; float bv = -1.f;
#pragma unroll
            for (int e = 0; e < E; ++e) { if (p[e] > bv) { bv = p[e]; best = e; } }
            sel[k] = best; wv[k] = bv; tot += bv; p[best] = -2.f;
        }
#pragma unroll
        for (int k = 0; k < TOPK; ++k) {
            topk_idx[wave * TOPK + k] = sel[k];
            topk_w[wave * TOPK + k] = wv[k] / tot;
            atomicAdd(&counts[sel[k]], 1);
        }
    }
}

__global__ void scan_kernel(const int* __restrict__ counts, int* __restrict__ offsets)
{
    if (threadIdx.x == 0 && blockIdx.x == 0) {
        int s = 0;
#pragma unroll
        for (int e = 0; e < E; ++e) { offsets[e] = s; s += counts[e]; }
        offsets[E] = s;
    }
}

__global__ __launch_bounds__(256) void scatter_kernel(
    const int* __restrict__ topk_idx, const float* __restrict__ topk_w,
    const int* __restrict__ offsets, int* __restrict__ cursor,
    int* __restrict__ pair_token, float* __restrict__ pair_w)
{
    int i = blockIdx.x * blockDim.x + threadIdx.x;
    if (i >= NPAIR) return;
    int e = topk_idx[i];
    int pos = offsets[e] + atomicAdd(&cursor[e], 1);
    pair_token[pos] = i >> 2;
    pair_w[pos] = topk_w[i];
}

// ---------------- GEMM A (MFMA): act = silu(Xg@w1^T) * (Xg@w3^T) ----------------
// tile 128(tokens) x 64(I), BK=64 over H. 4 waves 2x2; wave = 64x32 = 4x2 MFMA tiles.
__global__ __launch_bounds__(256) void gemm_a_kernel(
    const unsigned short* __restrict__ xb,
    const unsigned short* __restrict__ wb1,
    const unsigned short* __restrict__ wb3,
    const int* __restrict__ offsets,
    const int* __restrict__ pair_token,
    unsigned short* __restrict__ act)
{
    __shared__ __align__(16) unsigned short Xs[128 * 72];   // rows padded to 72 bf16
    __shared__ __align__(16) unsigned short W1s[64 * 72];
    __shared__ __align__(16) unsigned short W3s[64 * 72];

    int e = blockIdx.z;
    int beg = offsets[e];
    int cnt = offsets[e + 1] - beg;
    int t0 = blockIdx.x * 128;
    if (t0 >= cnt) return;
    int n0 = blockIdx.y * 64;
    int tid = threadIdx.x;

    // Per-thread gathered source rows for X staging (4 slots of 16B per thread)
    const unsigned short* xrow[4];
#pragma unroll
    for (int i = 0; i < 4; ++i) {
        int row = (tid + i * 256) >> 3;
        int r = t0 + row;
        xrow[i] = (r < cnt) ? (xb + (size_t)pair_token[beg + r] * H) : nullptr;
    }

    int wave = tid >> 6, lane = tid & 63;
    int wr = wave >> 1, wc = wave & 1;
    int lm = lane & 15, lq = lane >> 4;

    f32x4 acc1[4][2], acc3[4][2];
#pragma unroll
    for (int mi = 0; mi < 4; ++mi)
#pragma unroll
        for (int nj = 0; nj < 2; ++nj) {
            acc1[mi][nj] = (f32x4){0.f, 0.f, 0.f, 0.f};
            acc3[mi][nj] = (f32x4){0.f, 0.f, 0.f, 0.f};
        }

    for (int k0 = 0; k0 < H; k0 += 64) {
        __syncthreads();
#pragma unroll
        for (int i = 0; i < 4; ++i) {   // X: 128 rows x 64 bf16 = 1024 16B-slots
            int slot = tid + i * 256;
            int row = slot >> 3, kq = slot & 7;
            uint4 v = make_uint4(0u, 0u, 0u, 0u);
            if (xrow[i]) v = *(const uint4*)(xrow[i] + k0 + kq * 8);
            *(uint4*)(Xs + row * 72 + kq * 8) = v;
        }
#pragma unroll
        for (int i = 0; i < 2; ++i) {   // W1/W3: 64 rows x 64 bf16 = 512 slots each
            int slot = tid + i * 256;
            int row = slot >> 3, kq = slot & 7;
            size_t off = (size_t)e * IDIM * H + (size_t)(n0 + row) * H + k0 + kq * 8;
            uint4 a = *(const uint4*)(wb1 + off);
            uint4 b = *(const uint4*)(wb3 + off);
            *(uint4*)(W1s + row * 72 + kq * 8) = a;
            *(uint4*)(W3s + row * 72 + kq * 8) = b;
        }
        __syncthreads();
#pragma unroll
        for (int ks = 0; ks < 2; ++ks) {
            bf16x8 af[4], b1[2], b3[2];
#pragma unroll
            for (int mi = 0; mi < 4; ++mi)
                af[mi] = *(const bf16x8*)(Xs + (wr * 64 + mi * 16 + lm) * 72 + ks * 32 + lq * 8);
#pragma unroll
            for (int nj = 0; nj < 2; ++nj) {
                int n = wc * 32 + nj * 16 + lm;
                b1[nj] = *(const bf16x8*)(W1s + n * 72 + ks * 32 + lq * 8);
                b3[nj] = *(const bf16x8*)(W3s + n * 72 + ks * 32 + lq * 8);
            }
#pragma unroll
            for (int mi = 0; mi < 4; ++mi)
#pragma unroll
                for (int nj = 0; nj < 2; ++nj) {
                    acc1[mi][nj] = __builtin_amdgcn_mfma_f32_16x16x32_bf16(af[mi], b1[nj], acc1[mi][nj], 0, 0, 0);
                    acc3[mi][nj] = __builtin_amdgcn_mfma_f32_16x16x32_bf16(af[mi], b3[nj], acc3[mi][nj], 0, 0, 0);
                }
        }
    }
    // epilogue: C/D layout col=lane&15, row=(lane>>4)*4+reg
#pragma unroll
    for (int mi = 0; mi < 4; ++mi) {
#pragma unroll
        for (int r = 0; r < 4; ++r) {
            int trow = t0 + wr * 64 + mi * 16 + lq * 4 + r;
            if (trow < cnt) {
                size_t base = (size_t)(beg + trow) * IDIM + n0 + wc * 32 + lm;
#pragma unroll
                for (int nj = 0; nj < 2; ++nj) {
                    float h1 = acc1[mi][nj][r];
                    float s = h1 / (1.f + __expf(-h1));
                    act[base + nj * 16] = f2bf(s * acc3[mi][nj][r]);
                }
            }
        }
    }
}

// ---------------- GEMM B (MFMA): out[tok,:] += pw * act @ w2^T ----------------
__global__ __launch_bounds__(256) void gemm_b_kernel(
    const unsigned short* __restrict__ act,
    const unsigned short* __restrict__ wb2,
    const int* __restrict__ offsets,
    const int* __restrict__ pair_token,
    const float* __restrict__ pair_w,
    float* __restrict__ out)
{
    __shared__ __align__(16) unsigned short As[128 * 72];
    __shared__ __align__(16) unsigned short W2s[64 * 72];

    int e = blockIdx.z;
    int beg = offsets[e];
    int cnt = offsets[e + 1] - beg;
    int t0 = blockIdx.x * 128;
    if (t0 >= cnt) return;
    int h0 = blockIdx.y * 64;
    int tid = threadIdx.x;

    int wave = tid >> 6, lane = tid & 63;
    int wr = wave >> 1, wc = wave & 1;
    int lm = lane & 15, lq = lane >> 4;

    f32x4 acc[4][2];
#pragma unroll
    for (int mi = 0; mi < 4; ++mi)
#pragma unroll
        for (int nj = 0; nj < 2; ++nj) acc[mi][nj] = (f32x4){0.f, 0.f, 0.f, 0.f};

    for (int k0 = 0; k0 < IDIM; k0 += 64) {
        __syncthreads();
#pragma unroll
        for (int i = 0; i < 4; ++i) {   // act rows are contiguous (grouped); clamp tail
            int slot = tid + i * 256;
            int row = slot >> 3, kq = slot & 7;
            int ar = beg + t0 + row; if (ar > NPAIR - 1) ar = NPAIR - 1;
            uint4 v = *(const uint4*)(act + (size_t)ar * IDIM + k0 + kq * 8);
            *(uint4*)(As + row * 72 + kq * 8) = v;
        }
#pragma unroll
        for (int i = 0; i < 2; ++i) {
            int slot = tid + i * 256;
            int row = slot >> 3, kq = slot & 7;
            size_t off = (size_t)e * H * IDIM + (size_t)(h0 + row) * IDIM + k0 + kq * 8;
            *(uint4*)(W2s + row * 72 + kq * 8) = *(const uint4*)(wb2 + off);
        }
        __syncthreads();
#pragma unroll
        for (int ks = 0; ks < 2; ++ks) {
            bf16x8 af[4], bf[2];
#pragma unroll
            for (int mi = 0; mi < 4; ++mi)
                af[mi] = *(const bf16x8*)(As + (wr * 64 + mi * 16 + lm) * 72 + ks * 32 + lq * 8);
#pragma unroll
            for (int nj = 0; nj < 2; ++nj)
                bf[nj] = *(const bf16x8*)(W2s + (wc * 32 + nj * 16 + lm) * 72 + ks * 32 + lq * 8);
#pragma unroll
            for (int mi = 0; mi < 4; ++mi)
#pragma unroll
                for (int nj = 0; nj < 2; ++nj)
                    acc[mi][nj] = __builtin_amdgcn_mfma_f32_16x16x32_bf16(af[mi], bf[nj], acc[mi][nj], 0, 0, 0);
        }
    }
#pragma unroll
    for (int mi = 0; mi < 4; ++mi) {
#pragma unroll
        for (int r = 0; r < 4; ++r) {
            int trow = t0 + wr * 64 + mi * 16 + lq * 4 + r;
            if (trow < cnt) {
                int tok = pair_token[beg + trow];
                float pw = pair_w[beg + trow];
                float* orow = out + (size_t)tok * H + h0 + wc * 32 + lm;
#pragma unroll
                for (int nj = 0; nj < 2; ++nj)
                    atomicAdd(&orow[nj * 16], pw * acc[mi][nj][r]);
            }
        }
    }
}

extern "C" void kernel_launch(void* const* d_in, const int* in_sizes, int n_in,
                              void* d_out, int out_size, void* d_ws, size_t ws_size,
                              hipStream_t stream)
{
    const float* x  = (const float*)d_in[0];
    const float* gw = (const float*)d_in[1];
    const float* w1 = (const float*)d_in[2];
    const float* w3 = (const float*)d_in[3];
    const float* w2 = (const float*)d_in[4];
    float* out = (float*)d_out;

    char* ws = (char*)d_ws;
    int*   counts     = (int*)(ws + 0);
    int*   cursor     = (int*)(ws + 64);
    int*   offsets    = (int*)(ws + 128);
    int*   topk_idx   = (int*)(ws + 1024);           // 32 KB
    float* topk_w     = (float*)(ws + 33792);        // 32 KB
    int*   pair_token = (int*)(ws + 66560);          // 32 KB
    float* pair_w     = (float*)(ws + 99328);        // 32 KB
    unsigned short* xb  = (unsigned short*)(ws + 262144);    // 4 MB
    unsigned short* wb1 = (unsigned short*)(ws + 8388608);   // 16 MB
    unsigned short* wb3 = (unsigned short*)(ws + 25165824);  // 16 MB
    unsigned short* wb2 = (unsigned short*)(ws + 41943040);  // 16 MB
    unsigned short* act = (unsigned short*)(ws + 58720256);  // 8 MB -> 64 MB total

    hipMemsetAsync(ws, 0, 256, stream);
    hipMemsetAsync(d_out, 0, (size_t)T * H * sizeof(float), stream);

    router_kernel<<<T / 4, 256, 0, stream>>>(x, gw, topk_idx, topk_w, counts);
    scan_kernel<<<1, 64, 0, stream>>>(counts, offsets);
    scatter_kernel<<<NPAIR / 256, 256, 0, stream>>>(topk_idx, topk_w, offsets, cursor,
                                                    pair_token, pair_w);

    cvt_kernel<<<512, 256, 0, stream>>>(x, xb, (T * H) / 4);
    cvt_kernel<<<2048, 256, 0, stream>>>(w1, wb1, (E * IDIM * H) / 4);
    cvt_kernel<<<2048, 256, 0, stream>>>(w3, wb3, (E * IDIM * H) / 4);
    cvt_kernel<<<2048, 256, 0, stream>>>(w2, wb2, (E * H * IDIM) / 4);

    gemm_a_kernel<<<dim3(16, IDIM / 64, E), 256, 0, stream>>>(xb, wb1, wb3, offsets,
                                                              pair_token, act);
    gemm_b_kernel<<<dim3(16, H / 64, E), 256, 0, stream>>>(act, wb2, offsets,
                                                           pair_token, pair_w, out);
}

// Round 3
// 458.309 us; speedup vs baseline: 2.5726x; 1.0724x over previous
//
#include <hip/hip_runtime.h>
#include <hip/hip_bf16.h>

#define T 2048
#define H 1024
#define IDIM 512
#define E 16
#define TOPK 4
#define NPAIR (T * TOPK)

typedef short bf16x8 __attribute__((ext_vector_type(8)));
typedef float f32x4 __attribute__((ext_vector_type(4)));

static __device__ __forceinline__ unsigned short f2bf(float f) {
    union { float f; unsigned int u; } v; v.f = f;
    unsigned int r = (v.u + 0x7FFFu + ((v.u >> 16) & 1u)) >> 16;  // RNE
    return (unsigned short)r;
}

// async global->LDS, 16B per lane; LDS dst = uniform base + lane*16
static __device__ __forceinline__ void async_ld16(const unsigned short* g, unsigned short* l) {
    __builtin_amdgcn_global_load_lds((const __attribute__((address_space(1))) void*)g,
                                     (__attribute__((address_space(3))) void*)l, 16, 0, 0);
}

// ---------------- fp32 -> bf16 bulk convert ----------------
__global__ __launch_bounds__(256) void cvt_kernel(
    const float* __restrict__ src, unsigned short* __restrict__ dst, int n4)
{
    int i = blockIdx.x * blockDim.x + threadIdx.x;
    int stride = gridDim.x * blockDim.x;
    for (; i < n4; i += stride) {
        float4 v = ((const float4*)src)[i];
        ushort4 o;
        o.x = f2bf(v.x); o.y = f2bf(v.y); o.z = f2bf(v.z); o.w = f2bf(v.w);
        ((ushort4*)dst)[i] = o;
    }
}

// ---------------- Router (fp32, exact routing) ----------------
__global__ __launch_bounds__(256) void router_kernel(
    const float* __restrict__ x, const float* __restrict__ gw,
    int* __restrict__ topk_idx, float* __restrict__ topk_w,
    int* __restrict__ counts)
{
    int wave = blockIdx.x * 4 + (threadIdx.x >> 6);
    int lane = threadIdx.x & 63;
    if (wave >= T) return;
    const float* xt = x + (size_t)wave * H;
    float xr[16];
#pragma unroll
    for (int j = 0; j < 16; ++j) xr[j] = xt[lane + j * 64];
    float logits[E];
#pragma unroll
    for (int e = 0; e < E; ++e) {
        const float* ge = gw + e * H;
        float acc = 0.f;
#pragma unroll
        for (int j = 0; j < 16; ++j) acc += xr[j] * ge[lane + j * 64];
#pragma unroll
        for (int off = 32; off; off >>= 1) acc += __shfl_xor(acc, off, 64);
        logits[e] = acc;
    }
    if (lane == 0) {
        float m = logits[0];
#pragma unroll
        for (int e = 1; e < E; ++e) m = fmaxf(m, logits[e]);
        float p[E];
#pragma unroll
        for (int e = 0; e < E; ++e) p[e] = __expf(logits[e] - m);
        int sel[TOPK]; float wv[TOPK]; float tot = 0.f;
#pragma unroll
        for (int k = 0; k < TOPK; ++k) {
            int best = 0; float bv = -1.f;
#pragma unroll
            for (int e = 0; e < E; ++e) { if (p[e] > bv) { bv = p[e]; best = e; } }
            sel[k] = best; wv[k] = bv; tot += bv; p[best] = -2.f;
        }
#pragma unroll
        for (int k = 0; k < TOPK; ++k) {
            topk_idx[wave * TOPK + k] = sel[k];
            topk_w[wave * TOPK + k] = wv[k] / tot;
            atomicAdd(&counts[sel[k]], 1);
        }
    }
}

__global__ void scan_kernel(const int* __restrict__ counts, int* __restrict__ offsets)
{
    if (threadIdx.x == 0 && blockIdx.x == 0) {
        int s = 0;
#pragma unroll
        for (int e = 0; e < E; ++e) { offsets[e] = s; s += counts[e]; }
        offsets[E] = s;
    }
}

__global__ __launch_bounds__(256) void scatter_kernel(
    const int* __restrict__ topk_idx, const float* __restrict__ topk_w,
    const int* __restrict__ offsets, int* __restrict__ cursor,
    int* __restrict__ pair_token, float* __restrict__ pair_w)
{
    int i = blockIdx.x * blockDim.x + threadIdx.x;
    if (i >= NPAIR) return;
    int e = topk_idx[i];
    int pos = offsets[e] + atomicAdd(&cursor[e], 1);
    pair_token[pos] = i >> 2;
    pair_w[pos] = topk_w[i];
}

// ---------------- GEMM A: act = silu(Xg@w1^T) * (Xg@w3^T) ----------------
// 128(tok) x 64(I) tile, BK=64, async load_lds double-buffer, 1 barrier/iter.
// LDS unpadded 64-wide rows; XOR swizzle applied on global-fetch side:
//   LDS[row][c] holds global chunk (c ^ (row&7)); reads use (cc ^ (row&7)).
__global__ __launch_bounds__(256) void gemm_a_kernel(
    const unsigned short* __restrict__ xb,
    const unsigned short* __restrict__ wb1,
    const unsigned short* __restrict__ wb3,
    const int* __restrict__ offsets,
    const int* __restrict__ pair_token,
    unsigned short* __restrict__ act)
{
    __shared__ unsigned short Xs[2][128 * 64];
    __shared__ unsigned short W1s[2][64 * 64];
    __shared__ unsigned short W3s[2][64 * 64];

    int e = blockIdx.z;
    int beg = offsets[e];
    int cnt = offsets[e + 1] - beg;
    int t0 = blockIdx.x * 128;
    if (t0 >= cnt) return;
    int n0 = blockIdx.y * 64;

    int tid = threadIdx.x;
    int wave = tid >> 6, lane = tid & 63;
    int lrow8 = lane >> 3;            // 0..7 within 8-row group
    int csw = (lane & 7) ^ lrow8;     // swizzled source chunk for this lane

    // per-lane global pointers (k-invariant part)
    const unsigned short* xg[4];
#pragma unroll
    for (int i = 0; i < 4; ++i) {
        int row = wave * 32 + i * 8 + lrow8;
        int r = t0 + row; if (r >= cnt) r = cnt - 1;  // clamp; masked at store
        xg[i] = xb + (size_t)pair_token[beg + r] * H + csw * 8;
    }
    const unsigned short* w1g[2];
    const unsigned short* w3g[2];
    size_t wbase = (size_t)e * IDIM * H;
#pragma unroll
    for (int i = 0; i < 2; ++i) {
        int row = wave * 16 + i * 8 + lrow8;
        w1g[i] = wb1 + wbase + (size_t)(n0 + row) * H + csw * 8;
        w3g[i] = wb3 + wbase + (size_t)(n0 + row) * H + csw * 8;
    }

    int wr = wave >> 1, wc = wave & 1;
    int lm = lane & 15, lq = lane >> 4;

    f32x4 acc1[4][2], acc3[4][2];
#pragma unroll
    for (int mi = 0; mi < 4; ++mi)
#pragma unroll
        for (int nj = 0; nj < 2; ++nj) {
            acc1[mi][nj] = (f32x4){0.f, 0.f, 0.f, 0.f};
            acc3[mi][nj] = (f32x4){0.f, 0.f, 0.f, 0.f};
        }

    // prologue: stage k=0 into buffer 0
#pragma unroll
    for (int i = 0; i < 4; ++i) async_ld16(xg[i], &Xs[0][(wave * 32 + i * 8) * 64]);
#pragma unroll
    for (int i = 0; i < 2; ++i) {
        async_ld16(w1g[i], &W1s[0][(wave * 16 + i * 8) * 64]);
        async_ld16(w3g[i], &W3s[0][(wave * 16 + i * 8) * 64]);
    }

    const int NK = H / 64;
    for (int kk = 0; kk < NK; ++kk) {
        int cur = kk & 1;
        __syncthreads();   // drains vmcnt: buf[cur] DMA complete; buf[cur^1] readers done
        if (kk + 1 < NK) {
            int nxt = cur ^ 1;
            int k1 = (kk + 1) * 64;
#pragma unroll
            for (int i = 0; i < 4; ++i) async_ld16(xg[i] + k1, &Xs[nxt][(wave * 32 + i * 8) * 64]);
#pragma unroll
            for (int i = 0; i < 2; ++i) {
                async_ld16(w1g[i] + k1, &W1s[nxt][(wave * 16 + i * 8) * 64]);
                async_ld16(w3g[i] + k1, &W3s[nxt][(wave * 16 + i * 8) * 64]);
            }
        }
#pragma unroll
        for (int ks = 0; ks < 2; ++ks) {
            int cc = ks * 4 + lq;
            bf16x8 af[4], b1[2], b3[2];
#pragma unroll
            for (int mi = 0; mi < 4; ++mi) {
                int m = wr * 64 + mi * 16 + lm;
                af[mi] = *(const bf16x8*)&Xs[cur][m * 64 + ((cc ^ (m & 7)) << 3)];
            }
#pragma unroll
            for (int nj = 0; nj < 2; ++nj) {
                int n = wc * 32 + nj * 16 + lm;
                b1[nj] = *(const bf16x8*)&W1s[cur][n * 64 + ((cc ^ (n & 7)) << 3)];
                b3[nj] = *(const bf16x8*)&W3s[cur][n * 64 + ((cc ^ (n & 7)) << 3)];
            }
#pragma unroll
            for (int mi = 0; mi < 4; ++mi)
#pragma unroll
                for (int nj = 0; nj < 2; ++nj) {
                    acc1[mi][nj] = __builtin_amdgcn_mfma_f32_16x16x32_bf16(af[mi], b1[nj], acc1[mi][nj], 0, 0, 0);
                    acc3[mi][nj] = __builtin_amdgcn_mfma_f32_16x16x32_bf16(af[mi], b3[nj], acc3[mi][nj], 0, 0, 0);
                }
        }
    }
    // epilogue: C/D layout col=lane&15, row=(lane>>4)*4+reg
#pragma unroll
    for (int mi = 0; mi < 4; ++mi) {
#pragma unroll
        for (int r = 0; r < 4; ++r) {
            int trow = t0 + wr * 64 + mi * 16 + lq * 4 + r;
            if (trow < cnt) {
                size_t base = (size_t)(beg + trow) * IDIM + n0 + wc * 32 + lm;
#pragma unroll
                for (int nj = 0; nj < 2; ++nj) {
                    float h1 = acc1[mi][nj][r];
                    float s = h1 / (1.f + __expf(-h1));
                    act[base + nj * 16] = f2bf(s * acc3[mi][nj][r]);
                }
            }
        }
    }
}

// ---------------- GEMM B: out[tok,:] += pw * act @ w2^T ----------------
__global__ __launch_bounds__(256) void gemm_b_kernel(
    const unsigned short* __restrict__ act,
    const unsigned short* __restrict__ wb2,
    const int* __restrict__ offsets,
    const int* __restrict__ pair_token,
    const float* __restrict__ pair_w,
    float* __restrict__ out)
{
    __shared__ unsigned short As[2][128 * 64];
    __shared__ unsigned short W2s[2][64 * 64];

    int e = blockIdx.z;
    int beg = offsets[e];
    int cnt = offsets[e + 1] - beg;
    int t0 = blockIdx.x * 128;
    if (t0 >= cnt) return;
    int h0 = blockIdx.y * 64;

    int tid = threadIdx.x;
    int wave = tid >> 6, lane = tid & 63;
    int lrow8 = lane >> 3;
    int csw = (lane & 7) ^ lrow8;

    const unsigned short* ag[4];
#pragma unroll
    for (int i = 0; i < 4; ++i) {
        int row = wave * 32 + i * 8 + lrow8;
        int ar = beg + t0 + row; if (ar > NPAIR - 1) ar = NPAIR - 1;
        ag[i] = act + (size_t)ar * IDIM + csw * 8;
    }
    const unsigned short* w2g[2];
    size_t wbase = (size_t)e * H * IDIM;
#pragma unroll
    for (int i = 0; i < 2; ++i) {
        int row = wave * 16 + i * 8 + lrow8;
        w2g[i] = wb2 + wbase + (size_t)(h0 + row) * IDIM + csw * 8;
    }

    int wr = wave >> 1, wc = wave & 1;
    int lm = lane & 15, lq = lane >> 4;

    f32x4 acc[4][2];
#pragma unroll
    for (int mi = 0; mi < 4; ++mi)
#pragma unroll
        for (int nj = 0; nj < 2; ++nj) acc[mi][nj] = (f32x4){0.f, 0.f, 0.f, 0.f};

#pragma unroll
    for (int i = 0; i < 4; ++i) async_ld16(ag[i], &As[0][(wave * 32 + i * 8) * 64]);
#pragma unroll
    for (int i = 0; i < 2; ++i) async_ld16(w2g[i], &W2s[0][(wave * 16 + i * 8) * 64]);

    const int NK = IDIM / 64;
    for (int kk = 0; kk < NK; ++kk) {
        int cur = kk & 1;
        __syncthreads();
        if (kk + 1 < NK) {
            int nxt = cur ^ 1;
            int k1 = (kk + 1) * 64;
#pragma unroll
            for (int i = 0; i < 4; ++i) async_ld16(ag[i] + k1, &As[nxt][(wave * 32 + i * 8) * 64]);
#pragma unroll
            for (int i = 0; i < 2; ++i) async_ld16(w2g[i] + k1, &W2s[nxt][(wave * 16 + i * 8) * 64]);
        }
#pragma unroll
        for (int ks = 0; ks < 2; ++ks) {
            int cc = ks * 4 + lq;
            bf16x8 af[4], bfr[2];
#pragma unroll
            for (int mi = 0; mi < 4; ++mi) {
                int m = wr * 64 + mi * 16 + lm;
                af[mi] = *(const bf16x8*)&As[cur][m * 64 + ((cc ^ (m & 7)) << 3)];
            }
#pragma unroll
            for (int nj = 0; nj < 2; ++nj) {
                int n = wc * 32 + nj * 16 + lm;
                bfr[nj] = *(const bf16x8*)&W2s[cur][n * 64 + ((cc ^ (n & 7)) << 3)];
            }
#pragma unroll
            for (int mi = 0; mi < 4; ++mi)
#pragma unroll
                for (int nj = 0; nj < 2; ++nj)
                    acc[mi][nj] = __builtin_amdgcn_mfma_f32_16x16x32_bf16(af[mi], bfr[nj], acc[mi][nj], 0, 0, 0);
        }
    }
#pragma unroll
    for (int mi = 0; mi < 4; ++mi) {
#pragma unroll
        for (int r = 0; r < 4; ++r) {
            int trow = t0 + wr * 64 + mi * 16 + lq * 4 + r;
            if (trow < cnt) {
                int tok = pair_token[beg + trow];
                float pw = pair_w[beg + trow];
                float* orow = out + (size_t)tok * H + h0 + wc * 32 + lm;
#pragma unroll
                for (int nj = 0; nj < 2; ++nj)
                    atomicAdd(&orow[nj * 16], pw * acc[mi][nj][r]);
            }
        }
    }
}

extern "C" void kernel_launch(void* const* d_in, const int* in_sizes, int n_in,
                              void* d_out, int out_size, void* d_ws, size_t ws_size,
                              hipStream_t stream)
{
    const float* x  = (const float*)d_in[0];
    const float* gw = (const float*)d_in[1];
    const float* w1 = (const float*)d_in[2];
    const float* w3 = (const float*)d_in[3];
    const float* w2 = (const float*)d_in[4];
    float* out = (float*)d_out;

    char* ws = (char*)d_ws;
    int*   counts     = (int*)(ws + 0);
    int*   cursor     = (int*)(ws + 64);
    int*   offsets    = (int*)(ws + 128);
    int*   topk_idx   = (int*)(ws + 1024);
    float* topk_w     = (float*)(ws + 33792);
    int*   pair_token = (int*)(ws + 66560);
    float* pair_w     = (float*)(ws + 99328);
    unsigned short* xb  = (unsigned short*)(ws + 262144);    // 4 MB
    unsigned short* wb1 = (unsigned short*)(ws + 8388608);   // 16 MB
    unsigned short* wb3 = (unsigned short*)(ws + 25165824);  // 16 MB
    unsigned short* wb2 = (unsigned short*)(ws + 41943040);  // 16 MB
    unsigned short* act = (unsigned short*)(ws + 58720256);  // 8 MB

    hipMemsetAsync(ws, 0, 256, stream);
    hipMemsetAsync(d_out, 0, (size_t)T * H * sizeof(float), stream);

    router_kernel<<<T / 4, 256, 0, stream>>>(x, gw, topk_idx, topk_w, counts);
    scan_kernel<<<1, 64, 0, stream>>>(counts, offsets);
    scatter_kernel<<<NPAIR / 256, 256, 0, stream>>>(topk_idx, topk_w, offsets, cursor,
                                                    pair_token, pair_w);

    cvt_kernel<<<512, 256, 0, stream>>>(x, xb, (T * H) / 4);
    cvt_kernel<<<2048, 256, 0, stream>>>(w1, wb1, (E * IDIM * H) / 4);
    cvt_kernel<<<2048, 256, 0, stream>>>(w3, wb3, (E * IDIM * H) / 4);
    cvt_kernel<<<2048, 256, 0, stream>>>(w2, wb2, (E * H * IDIM) / 4);

    gemm_a_kernel<<<dim3(16, IDIM / 64, E), 256, 0, stream>>>(xb, wb1, wb3, offsets,
                                                              pair_token, act);
    gemm_b_kernel<<<dim3(16, H / 64, E), 256, 0, stream>>>(act, wb2, offsets,
                                                           pair_token, pair_w, out);
}

// Round 4
// 319.989 us; speedup vs baseline: 3.6847x; 1.4323x over previous
//
#include <hip/hip_runtime.h>
#include <hip/hip_bf16.h>

#define T 2048
#define H 1024
#define IDIM 512
#define E 16
#define TOPK 4
#define NPAIR (T * TOPK)

typedef short bf16x8 __attribute__((ext_vector_type(8)));
typedef float f32x4 __attribute__((ext_vector_type(4)));

static __device__ __forceinline__ unsigned short f2bf(float f) {
    union { float f; unsigned int u; } v; v.f = f;
    unsigned int r = (v.u + 0x7FFFu + ((v.u >> 16) & 1u)) >> 16;  // RNE
    return (unsigned short)r;
}

static __device__ __forceinline__ void async_ld16(const unsigned short* g, unsigned short* l) {
    __builtin_amdgcn_global_load_lds((const __attribute__((address_space(1))) void*)g,
                                     (__attribute__((address_space(3))) void*)l, 16, 0, 0);
}

// ---------------- fp32 -> bf16 bulk convert ----------------
__global__ __launch_bounds__(256) void cvt_kernel(
    const float* __restrict__ src, unsigned short* __restrict__ dst, int n4)
{
    int i = blockIdx.x * blockDim.x + threadIdx.x;
    int stride = gridDim.x * blockDim.x;
    for (; i < n4; i += stride) {
        float4 v = ((const float4*)src)[i];
        ushort4 o;
        o.x = f2bf(v.x); o.y = f2bf(v.y); o.z = f2bf(v.z); o.w = f2bf(v.w);
        ((ushort4*)dst)[i] = o;
    }
}

// ---------------- Router (fp32, exact routing) — NO atomics ----------------
__global__ __launch_bounds__(256) void router_kernel(
    const float* __restrict__ x, const float* __restrict__ gw,
    int* __restrict__ topk_idx, float* __restrict__ topk_w)
{
    int wave = blockIdx.x * 4 + (threadIdx.x >> 6);
    int lane = threadIdx.x & 63;
    if (wave >= T) return;
    const float* xt = x + (size_t)wave * H;
    float xr[16];
#pragma unroll
    for (int j = 0; j < 16; ++j) xr[j] = xt[lane + j * 64];
    float logits[E];
#pragma unroll
    for (int e = 0; e < E; ++e) {
        const float* ge = gw + e * H;
        float acc = 0.f;
#pragma unroll
        for (int j = 0; j < 16; ++j) acc += xr[j] * ge[lane + j * 64];
#pragma unroll
        for (int off = 32; off; off >>= 1) acc += __shfl_xor(acc, off, 64);
        logits[e] = acc;
    }
    if (lane == 0) {
        float m = logits[0];
#pragma unroll
        for (int e = 1; e < E; ++e) m = fmaxf(m, logits[e]);
        float p[E];
#pragma unroll
        for (int e = 0; e < E; ++e) p[e] = __expf(logits[e] - m);
        int sel[TOPK]; float wv[TOPK]; float tot = 0.f;
#pragma unroll
        for (int k = 0; k < TOPK; ++k) {
            int best = 0; float bv = -1.f;
#pragma unroll
            for (int e = 0; e < E; ++e) { if (p[e] > bv) { bv = p[e]; best = e; } }
            sel[k] = best; wv[k] = bv; tot += bv; p[best] = -2.f;
        }
#pragma unroll
        for (int k = 0; k < TOPK; ++k) {
            topk_idx[wave * TOPK + k] = sel[k];
            topk_w[wave * TOPK + k] = wv[k] / tot;
        }
    }
}

// ---------------- Histogram + exclusive scan (one block, LDS only) ----------------
__global__ __launch_bounds__(256) void hist_kernel(
    const int* __restrict__ topk_idx, int* __restrict__ offsets)
{
    __shared__ int h[4][E];
    int tid = threadIdx.x, wave = tid >> 6;
    if (tid < 4 * E) ((int*)h)[tid] = 0;
    __syncthreads();
    for (int i = tid; i < NPAIR; i += 256) atomicAdd(&h[wave][topk_idx[i]], 1);
    __syncthreads();
    if (tid == 0) {
        int s = 0;
#pragma unroll
        for (int e = 0; e < E; ++e) {
            offsets[e] = s;
            s += h[0][e] + h[1][e] + h[2][e] + h[3][e];
        }
        offsets[E] = s;
    }
}

// ---------------- Scatter: LDS local ranks, 16 global atomics/block ----------------
__global__ __launch_bounds__(256) void scatter_kernel(
    const int* __restrict__ topk_idx,
    const int* __restrict__ offsets, int* __restrict__ cursor,
    int* __restrict__ pair_token, int* __restrict__ inv_pos)
{
    __shared__ int lh[E];
    __shared__ int base[E];
    int tid = threadIdx.x;
    int i = blockIdx.x * 256 + tid;
    if (tid < E) lh[tid] = 0;
    __syncthreads();
    int e = topk_idx[i];
    int lr = atomicAdd(&lh[e], 1);           // LDS atomic
    __syncthreads();
    if (tid < E) base[tid] = atomicAdd(&cursor[tid], lh[tid]);  // 16 global/block
    __syncthreads();
    int pos = offsets[e] + base[e] + lr;
    pair_token[pos] = i >> 2;
    inv_pos[i] = pos;
}

// ---------------- GEMM A: act = silu(Xg@w1^T) * (Xg@w3^T) ----------------
__global__ __launch_bounds__(256) void gemm_a_kernel(
    const unsigned short* __restrict__ xb,
    const unsigned short* __restrict__ wb1,
    const unsigned short* __restrict__ wb3,
    const int* __restrict__ offsets,
    const int* __restrict__ pair_token,
    unsigned short* __restrict__ act)
{
    __shared__ unsigned short Xs[2][128 * 64];
    __shared__ unsigned short W1s[2][64 * 64];
    __shared__ unsigned short W3s[2][64 * 64];

    int e = blockIdx.z;
    int beg = offsets[e];
    int cnt = offsets[e + 1] - beg;
    int t0 = blockIdx.x * 128;
    if (t0 >= cnt) return;
    int n0 = blockIdx.y * 64;

    int tid = threadIdx.x;
    int wave = tid >> 6, lane = tid & 63;
    int lrow8 = lane >> 3;
    int csw = (lane & 7) ^ lrow8;

    const unsigned short* xg[4];
#pragma unroll
    for (int i = 0; i < 4; ++i) {
        int row = wave * 32 + i * 8 + lrow8;
        int r = t0 + row; if (r >= cnt) r = cnt - 1;
        xg[i] = xb + (size_t)pair_token[beg + r] * H + csw * 8;
    }
    const unsigned short* w1g[2];
    const unsigned short* w3g[2];
    size_t wbase = (size_t)e * IDIM * H;
#pragma unroll
    for (int i = 0; i < 2; ++i) {
        int row = wave * 16 + i * 8 + lrow8;
        w1g[i] = wb1 + wbase + (size_t)(n0 + row) * H + csw * 8;
        w3g[i] = wb3 + wbase + (size_t)(n0 + row) * H + csw * 8;
    }

    int wr = wave >> 1, wc = wave & 1;
    int lm = lane & 15, lq = lane >> 4;

    f32x4 acc1[4][2], acc3[4][2];
#pragma unroll
    for (int mi = 0; mi < 4; ++mi)
#pragma unroll
        for (int nj = 0; nj < 2; ++nj) {
            acc1[mi][nj] = (f32x4){0.f, 0.f, 0.f, 0.f};
            acc3[mi][nj] = (f32x4){0.f, 0.f, 0.f, 0.f};
        }

#pragma unroll
    for (int i = 0; i < 4; ++i) async_ld16(xg[i], &Xs[0][(wave * 32 + i * 8) * 64]);
#pragma unroll
    for (int i = 0; i < 2; ++i) {
        async_ld16(w1g[i], &W1s[0][(wave * 16 + i * 8) * 64]);
        async_ld16(w3g[i], &W3s[0][(wave * 16 + i * 8) * 64]);
    }

    const int NK = H / 64;
    for (int kk = 0; kk < NK; ++kk) {
        int cur = kk & 1;
        __syncthreads();
        if (kk + 1 < NK) {
            int nxt = cur ^ 1;
            int k1 = (kk + 1) * 64;
#pragma unroll
            for (int i = 0; i < 4; ++i) async_ld16(xg[i] + k1, &Xs[nxt][(wave * 32 + i * 8) * 64]);
#pragma unroll
            for (int i = 0; i < 2; ++i) {
                async_ld16(w1g[i] + k1, &W1s[nxt][(wave * 16 + i * 8) * 64]);
                async_ld16(w3g[i] + k1, &W3s[nxt][(wave * 16 + i * 8) * 64]);
            }
        }
#pragma unroll
        for (int ks = 0; ks < 2; ++ks) {
            int cc = ks * 4 + lq;
            bf16x8 af[4], b1[2], b3[2];
#pragma unroll
            for (int mi = 0; mi < 4; ++mi) {
                int m = wr * 64 + mi * 16 + lm;
                af[mi] = *(const bf16x8*)&Xs[cur][m * 64 + ((cc ^ (m & 7)) << 3)];
            }
#pragma unroll
            for (int nj = 0; nj < 2; ++nj) {
                int n = wc * 32 + nj * 16 + lm;
                b1[nj] = *(const bf16x8*)&W1s[cur][n * 64 + ((cc ^ (n & 7)) << 3)];
                b3[nj] = *(const bf16x8*)&W3s[cur][n * 64 + ((cc ^ (n & 7)) << 3)];
            }
#pragma unroll
            for (int mi = 0; mi < 4; ++mi)
#pragma unroll
                for (int nj = 0; nj < 2; ++nj) {
                    acc1[mi][nj] = __builtin_amdgcn_mfma_f32_16x16x32_bf16(af[mi], b1[nj], acc1[mi][nj], 0, 0, 0);
                    acc3[mi][nj] = __builtin_amdgcn_mfma_f32_16x16x32_bf16(af[mi], b3[nj], acc3[mi][nj], 0, 0, 0);
                }
        }
    }
#pragma unroll
    for (int mi = 0; mi < 4; ++mi) {
#pragma unroll
        for (int r = 0; r < 4; ++r) {
            int trow = t0 + wr * 64 + mi * 16 + lq * 4 + r;
            if (trow < cnt) {
                size_t base = (size_t)(beg + trow) * IDIM + n0 + wc * 32 + lm;
#pragma unroll
                for (int nj = 0; nj < 2; ++nj) {
                    float h1 = acc1[mi][nj][r];
                    float s = h1 / (1.f + __expf(-h1));
                    act[base + nj * 16] = f2bf(s * acc3[mi][nj][r]);
                }
            }
        }
    }
}

// ---------------- GEMM B: outp[pos,:] = act @ w2^T  (no atomics) ----------------
__global__ __launch_bounds__(256) void gemm_b_kernel(
    const unsigned short* __restrict__ act,
    const unsigned short* __restrict__ wb2,
    const int* __restrict__ offsets,
    float* __restrict__ outp)
{
    __shared__ unsigned short As[2][128 * 64];
    __shared__ unsigned short W2s[2][64 * 64];

    int e = blockIdx.z;
    int beg = offsets[e];
    int cnt = offsets[e + 1] - beg;
    int t0 = blockIdx.x * 128;
    if (t0 >= cnt) return;
    int h0 = blockIdx.y * 64;

    int tid = threadIdx.x;
    int wave = tid >> 6, lane = tid & 63;
    int lrow8 = lane >> 3;
    int csw = (lane & 7) ^ lrow8;

    const unsigned short* ag[4];
#pragma unroll
    for (int i = 0; i < 4; ++i) {
        int row = wave * 32 + i * 8 + lrow8;
        int ar = beg + t0 + row; if (ar > NPAIR - 1) ar = NPAIR - 1;
        ag[i] = act + (size_t)ar * IDIM + csw * 8;
    }
    const unsigned short* w2g[2];
    size_t wbase = (size_t)e * H * IDIM;
#pragma unroll
    for (int i = 0; i < 2; ++i) {
        int row = wave * 16 + i * 8 + lrow8;
        w2g[i] = wb2 + wbase + (size_t)(h0 + row) * IDIM + csw * 8;
    }

    int wr = wave >> 1, wc = wave & 1;
    int lm = lane & 15, lq = lane >> 4;

    f32x4 acc[4][2];
#pragma unroll
    for (int mi = 0; mi < 4; ++mi)
#pragma unroll
        for (int nj = 0; nj < 2; ++nj) acc[mi][nj] = (f32x4){0.f, 0.f, 0.f, 0.f};

#pragma unroll
    for (int i = 0; i < 4; ++i) async_ld16(ag[i], &As[0][(wave * 32 + i * 8) * 64]);
#pragma unroll
    for (int i = 0; i < 2; ++i) async_ld16(w2g[i], &W2s[0][(wave * 16 + i * 8) * 64]);

    const int NK = IDIM / 64;
    for (int kk = 0; kk < NK; ++kk) {
        int cur = kk & 1;
        __syncthreads();
        if (kk + 1 < NK) {
            int nxt = cur ^ 1;
            int k1 = (kk + 1) * 64;
#pragma unroll
            for (int i = 0; i < 4; ++i) async_ld16(ag[i] + k1, &As[nxt][(wave * 32 + i * 8) * 64]);
#pragma unroll
            for (int i = 0; i < 2; ++i) async_ld16(w2g[i] + k1, &W2s[nxt][(wave * 16 + i * 8) * 64]);
        }
#pragma unroll
        for (int ks = 0; ks < 2; ++ks) {
            int cc = ks * 4 + lq;
            bf16x8 af[4], bfr[2];
#pragma unroll
            for (int mi = 0; mi < 4; ++mi) {
                int m = wr * 64 + mi * 16 + lm;
                af[mi] = *(const bf16x8*)&As[cur][m * 64 + ((cc ^ (m & 7)) << 3)];
            }
#pragma unroll
            for (int nj = 0; nj < 2; ++nj) {
                int n = wc * 32 + nj * 16 + lm;
                bfr[nj] = *(const bf16x8*)&W2s[cur][n * 64 + ((cc ^ (n & 7)) << 3)];
            }
#pragma unroll
            for (int mi = 0; mi < 4; ++mi)
#pragma unroll
                for (int nj = 0; nj < 2; ++nj)
                    acc[mi][nj] = __builtin_amdgcn_mfma_f32_16x16x32_bf16(af[mi], bfr[nj], acc[mi][nj], 0, 0, 0);
        }
    }
#pragma unroll
    for (int mi = 0; mi < 4; ++mi) {
#pragma unroll
        for (int r = 0; r < 4; ++r) {
            int trow = t0 + wr * 64 + mi * 16 + lq * 4 + r;
            if (trow < cnt) {
                float* orow = outp + (size_t)(beg + trow) * H + h0 + wc * 32 + lm;
#pragma unroll
                for (int nj = 0; nj < 2; ++nj) orow[nj * 16] = acc[mi][nj][r];
            }
        }
    }
}

// ---------------- Combine: out[t,:] = sum_k w_k * outp[pos_k,:] ----------------
__global__ __launch_bounds__(256) void combine_kernel(
    const float* __restrict__ outp, const int* __restrict__ inv_pos,
    const float* __restrict__ topk_w, float* __restrict__ out)
{
    int gid = blockIdx.x * 256 + threadIdx.x;   // T * (H/4) threads
    int t = gid >> 8;
    int c4 = gid & 255;
    float4 a = make_float4(0.f, 0.f, 0.f, 0.f);
#pragma unroll
    for (int k = 0; k < TOPK; ++k) {
        int pos = inv_pos[t * TOPK + k];
        float w = topk_w[t * TOPK + k];
        float4 v = *(const float4*)(outp + (size_t)pos * H + c4 * 4);
        a.x += w * v.x; a.y += w * v.y; a.z += w * v.z; a.w += w * v.w;
    }
    *(float4*)(out + (size_t)t * H + c4 * 4) = a;
}

extern "C" void kernel_launch(void* const* d_in, const int* in_sizes, int n_in,
                              void* d_out, int out_size, void* d_ws, size_t ws_size,
                              hipStream_t stream)
{
    const float* x  = (const float*)d_in[0];
    const float* gw = (const float*)d_in[1];
    const float* w1 = (const float*)d_in[2];
    const float* w3 = (const float*)d_in[3];
    const float* w2 = (const float*)d_in[4];
    float* out = (float*)d_out;

    char* ws = (char*)d_ws;
    int*   cursor     = (int*)(ws + 64);
    int*   offsets    = (int*)(ws + 128);
    int*   topk_idx   = (int*)(ws + 1024);
    float* topk_w     = (float*)(ws + 33792);
    int*   pair_token = (int*)(ws + 66560);
    int*   inv_pos    = (int*)(ws + 99328);
    unsigned short* xb  = (unsigned short*)(ws + 262144);    // 4 MB
    unsigned short* wb1 = (unsigned short*)(ws + 8388608);   // 16 MB
    unsigned short* wb3 = (unsigned short*)(ws + 25165824);  // 16 MB
    unsigned short* wb2 = (unsigned short*)(ws + 41943040);  // 16 MB
    unsigned short* act = (unsigned short*)(ws + 58720256);  // 8 MB
    // outp aliases wb1+wb3 (dead after gemm_a): 8 MB pairs x H x fp32 = 32 MB
    float* outp = (float*)(ws + 8388608);

    hipMemsetAsync(ws, 0, 256, stream);   // cursor

    router_kernel<<<T / 4, 256, 0, stream>>>(x, gw, topk_idx, topk_w);
    hist_kernel<<<1, 256, 0, stream>>>(topk_idx, offsets);
    scatter_kernel<<<NPAIR / 256, 256, 0, stream>>>(topk_idx, offsets, cursor,
                                                    pair_token, inv_pos);

    cvt_kernel<<<512, 256, 0, stream>>>(x, xb, (T * H) / 4);
    cvt_kernel<<<2048, 256, 0, stream>>>(w1, wb1, (E * IDIM * H) / 4);
    cvt_kernel<<<2048, 256, 0, stream>>>(w3, wb3, (E * IDIM * H) / 4);
    cvt_kernel<<<2048, 256, 0, stream>>>(w2, wb2, (E * H * IDIM) / 4);

    gemm_a_kernel<<<dim3(16, IDIM / 64, E), 256, 0, stream>>>(xb, wb1, wb3, offsets,
                                                              pair_token, act);
    gemm_b_kernel<<<dim3(16, H / 64, E), 256, 0, stream>>>(act, wb2, offsets, outp);
    combine_kernel<<<(T * H / 4) / 256, 256, 0, stream>>>(outp, inv_pos, topk_w, out);
}